// Round 8
// baseline (32.212 us; speedup 1.0000x reference)
//
#include <hip/hip_runtime.h>

// Sobel3D: data [4,1,256,256,64] f32 -> out [4,1,256,256,64] f32 (0/1).
// out = 1 iff >=2 of the 3 directional Sobel gradients are nonzero.
//
// Separable decomposition (cross-correlation, SAME zero padding):
//   per (d,h) row:  S[i] = x[i-1]+2x[i]+x[i+1],  D[i] = x[i-1]-x[i+1]
//   per plane d:    ds = D(h-1)+D(h)+D(h+1), ss = S(h-1)+S(h)+S(h+1),
//                   sd = S(h-1)-S(h+1)
//   Gx = ds(d-1)+2*ds(d)+ds(d+1); Gy = ss(d-1)-ss(d+1); Gz = sd(d-1)+sd(d)+sd(d+1)
//
// R8 = R6 structure with plain stores (NT-store was R6's suspected regressor)
//      + mask-logic emit (3 v_cmp + SALU instead of add-chain).
//  - 1-row x 4-w thread tile (keeps VGPR <= 64 -> 8 waves/SIMD; R7 showed
//    bigger tiles lose more from occupancy than they gain in instr count).
//  - depth-3 prefetch: ring of 4 raw plane buffers, 9 float4 loads in flight
//    at every consume point.
//  - DC=8: d-halo redundancy 1.25x; grid (32,32,4) = 4096 blocks x 2 waves.
//  - w-halo via DPP row_shr:1/row_shl:1 with bound_ctrl zero-fill.

constexpr int DDIM = 256;
constexpr int HDIM = 256;
constexpr int WWID = 64;
constexpr int DC   = 8;    // output d-planes per block
constexpr int HT   = 8;    // h rows per block (2 waves)

typedef float vfloat4 __attribute__((ext_vector_type(4)));

struct P3  { float ds[4], ss[4], sd[4]; };
struct Raw { float4 a, b, c; };

__device__ __forceinline__ float dpp_up1(float v) {   // lane n <- lane n-1 (16-lane row), edge->0
  return __builtin_bit_cast(float, __builtin_amdgcn_update_dpp(
      0, __builtin_bit_cast(int, v), 0x111, 0xf, 0xf, true));  // row_shr:1
}
__device__ __forceinline__ float dpp_dn1(float v) {   // lane n <- lane n+1 (16-lane row), edge->0
  return __builtin_bit_cast(float, __builtin_amdgcn_update_dpp(
      0, __builtin_bit_cast(int, v), 0x101, 0xf, 0xf, true));  // row_shl:1
}

__global__ __launch_bounds__(128) void sobel3d_kernel(
    const float* __restrict__ in, float* __restrict__ out) {
  const int lane = threadIdx.x;          // 0..63
  const int wg   = lane & 15;            // w-group within row (16 x float4 = row)
  const int hs   = lane >> 4;            // h-sub within wave
  const int w0   = wg * 4;
  const int h    = blockIdx.x * HT + threadIdx.y * 4 + hs;
  const int d0   = blockIdx.y * DC;
  const int b    = blockIdx.z;

  const size_t plane = (size_t)HDIM * WWID;   // 16384 floats
  const float* src = in  + (size_t)b * DDIM * plane;
  float*       dst = out + (size_t)b * DDIM * plane;

  const size_t offb = (size_t)h * WWID + w0;  // this thread's row base
  const bool va = (h > 0);                    // h-1 valid
  const bool vc = (h + 1 < HDIM);             // h+1 valid

  auto loadPlane = [&](int d, Raw& r) {
    if ((unsigned)d < (unsigned)DDIM) {
      const float* p = src + (size_t)d * plane;
      r.b = *(const float4*)(p + offb);
      r.a = va ? *(const float4*)(p + offb - WWID) : float4{0.f, 0.f, 0.f, 0.f};
      r.c = vc ? *(const float4*)(p + offb + WWID) : float4{0.f, 0.f, 0.f, 0.f};
    } else {
      r.a = r.b = r.c = float4{0.f, 0.f, 0.f, 0.f};
    }
  };

  // row partials S (1,2,1) and D (1,0,-1) at the 4 output w positions
  auto rowSD = [&](float4 v, float* S, float* D) {
    const float x1 = (v.x == 255.f) ? 0.f : v.x;   // reference where()
    const float x2 = (v.y == 255.f) ? 0.f : v.y;
    const float x3 = (v.z == 255.f) ? 0.f : v.z;
    const float x4 = (v.w == 255.f) ? 0.f : v.w;
    const float xm = dpp_up1(x4);   // x[w0-1] (0 at w-edge)
    const float xp = dpp_dn1(x1);   // x[w0+4] (0 at w-edge)
    const float x[6] = {xm, x1, x2, x3, x4, xp};
    #pragma unroll
    for (int i = 0; i < 4; ++i) {
      S[i] = fmaf(2.f, x[i + 1], x[i]) + x[i + 2];
      D[i] = x[i] - x[i + 2];
    }
  };

  auto partials = [&](const Raw& r, P3& o) {
    float Sa[4], Da[4], Sb[4], Db[4], Sc[4], Dc[4];
    rowSD(r.a, Sa, Da);
    rowSD(r.b, Sb, Db);
    rowSD(r.c, Sc, Dc);
    #pragma unroll
    for (int i = 0; i < 4; ++i) {
      o.ds[i] = Da[i] + Db[i] + Dc[i];
      o.ss[i] = Sa[i] + Sb[i] + Sc[i];
      o.sd[i] = Sa[i] - Sc[i];
    }
  };

  auto emit = [&](int d, const P3& p, const P3& c, const P3& n) {
    vfloat4 o;
    #pragma unroll
    for (int i = 0; i < 4; ++i) {
      const float Gx = fmaf(2.f, c.ds[i], p.ds[i]) + n.ds[i];
      const float Gy = p.ss[i] - n.ss[i];
      const float Gz = p.sd[i] + c.sd[i] + n.sd[i];
      const int nx = (Gx != 0.f), ny = (Gy != 0.f), nz = (Gz != 0.f);
      o[i] = ((nx & ny) | (nx & nz) | (ny & nz)) ? 1.f : 0.f;
    }
    *(vfloat4*)(dst + (size_t)d * plane + offb) = o;
  };

  Raw A, B, C, D;          // 4-buffer raw-plane ring
  P3 p0, p1, p2;           // 3-slot partials ring

  // depth-3 software pipeline over planes d0-1 .. d0+8 (10 loads, 8 outputs)
  loadPlane(d0 - 1, A);
  loadPlane(d0,     B);
  loadPlane(d0 + 1, C);
  loadPlane(d0 + 2, D);
  partials(A, p0);  loadPlane(d0 + 3, A);
  partials(B, p1);  loadPlane(d0 + 4, B);
  partials(C, p2);  emit(d0,     p0, p1, p2);  loadPlane(d0 + 5, C);
  partials(D, p0);  emit(d0 + 1, p1, p2, p0);  loadPlane(d0 + 6, D);
  partials(A, p1);  emit(d0 + 2, p2, p0, p1);  loadPlane(d0 + 7, A);
  partials(B, p2);  emit(d0 + 3, p0, p1, p2);  loadPlane(d0 + 8, B);
  partials(C, p0);  emit(d0 + 4, p1, p2, p0);
  partials(D, p1);  emit(d0 + 5, p2, p0, p1);
  partials(A, p2);  emit(d0 + 6, p0, p1, p2);
  partials(B, p0);  emit(d0 + 7, p1, p2, p0);
}

extern "C" void kernel_launch(void* const* d_in, const int* in_sizes, int n_in,
                              void* d_out, int out_size, void* d_ws, size_t ws_size,
                              hipStream_t stream) {
  const float* data = (const float*)d_in[0];
  // d_in[1] = Sobel weights — fixed by the reference, folded into the kernel.
  float* out = (float*)d_out;
  dim3 grid(HDIM / HT, DDIM / DC, 4);   // (32, 32, 4) = 4096 blocks
  dim3 block(WWID, 2);                  // 128 threads = 2 waves
  sobel3d_kernel<<<grid, block, 0, stream>>>(data, out);
}

// Round 9
// 30.944 us; speedup vs baseline: 1.0410x; 1.0410x over previous
//
#include <hip/hip_runtime.h>

// Sobel3D: data [4,1,256,256,64] f32 -> out [4,1,256,256,64] f32 (0/1).
// out = 1 iff >=2 of the 3 directional Sobel gradients are nonzero.
//
// Separable decomposition (cross-correlation, SAME zero padding):
//   per (d,h) row:  S[i] = x[i-1]+2x[i]+x[i+1],  D[i] = x[i-1]-x[i+1]
//   per plane d:    ds = D(h-1)+D(h)+D(h+1), ss = S(h-1)+S(h)+S(h+1),
//                   sd = S(h-1)-S(h+1)
//   Gx = ds(d-1)+2*ds(d)+ds(d+1); Gy = ss(d-1)-ss(d+1); Gz = sd(d-1)+sd(d)+sd(d+1)
//
// R9 = exact R4 skeleton (best: 30.3us) + two hot-path trims:
//  - mask-logic emit: (nx&ny)|(nx&nz)|(ny&nz) instead of count>=2 add-chain.
//  - interior/edge specialization: blocks with d0 in [1, 251] and h-tile not
//    touching h=0/255 run a guard-free path (no per-plane bounds compare, no
//    per-lane h cndmask) -> straight-line loads the scheduler can hoist.
// Invariants from R6/R7/R8 post-mortems: VGPR <= 64 (8 waves/SIMD), DC=4
// all-6-planes-upfront pipeline, 8192 blocks, plain stores.

constexpr int DDIM = 256;
constexpr int HDIM = 256;
constexpr int WWID = 64;
constexpr int DC   = 4;    // output d-planes per block
constexpr int HT   = 8;    // h rows per block (2 waves)

typedef float vfloat4 __attribute__((ext_vector_type(4)));

struct P3 { float ds[4], ss[4], sd[4]; };

__device__ __forceinline__ float dpp_up1(float v) {   // lane n <- lane n-1 (16-lane row), edge->0
  return __builtin_bit_cast(float, __builtin_amdgcn_update_dpp(
      0, __builtin_bit_cast(int, v), 0x111, 0xf, 0xf, true));  // row_shr:1
}
__device__ __forceinline__ float dpp_dn1(float v) {   // lane n <- lane n+1 (16-lane row), edge->0
  return __builtin_bit_cast(float, __builtin_amdgcn_update_dpp(
      0, __builtin_bit_cast(int, v), 0x101, 0xf, 0xf, true));  // row_shl:1
}

template <bool EDGE>
__device__ __forceinline__ void sobel_body(
    const float* __restrict__ src, float* __restrict__ dst,
    int h, int d0, size_t offb) {
  constexpr size_t plane = (size_t)HDIM * WWID;   // 16384 floats

  const bool va = !EDGE || (h > 0);
  const bool vc = !EDGE || (h + 1 < HDIM);

  auto loadPlane = [&](int d, float4& ra, float4& rb, float4& rc) {
    if (!EDGE || (unsigned)d < (unsigned)DDIM) {
      const float* p = src + (size_t)d * plane;
      rb = *(const float4*)(p + offb);
      ra = va ? *(const float4*)(p + offb - WWID) : float4{0.f, 0.f, 0.f, 0.f};
      rc = vc ? *(const float4*)(p + offb + WWID) : float4{0.f, 0.f, 0.f, 0.f};
    } else {
      ra = rb = rc = float4{0.f, 0.f, 0.f, 0.f};
    }
  };

  // row partials S (1,2,1) and D (1,0,-1) at the 4 output w positions
  auto rowSD = [&](float4 v, float* S, float* D) {
    const float x1 = (v.x == 255.f) ? 0.f : v.x;   // reference where()
    const float x2 = (v.y == 255.f) ? 0.f : v.y;
    const float x3 = (v.z == 255.f) ? 0.f : v.z;
    const float x4 = (v.w == 255.f) ? 0.f : v.w;
    const float xm = dpp_up1(x4);   // x[w0-1] (0 at w-edge)
    const float xp = dpp_dn1(x1);   // x[w0+4] (0 at w-edge)
    const float x[6] = {xm, x1, x2, x3, x4, xp};
    #pragma unroll
    for (int i = 0; i < 4; ++i) {
      S[i] = fmaf(2.f, x[i + 1], x[i]) + x[i + 2];
      D[i] = x[i] - x[i + 2];
    }
  };

  auto partials = [&](const float4& ra, const float4& rb, const float4& rc, P3& o) {
    float Sa[4], Da[4], Sb[4], Db[4], Sc[4], Dc[4];
    rowSD(ra, Sa, Da);
    rowSD(rb, Sb, Db);
    rowSD(rc, Sc, Dc);
    #pragma unroll
    for (int i = 0; i < 4; ++i) {
      o.ds[i] = Da[i] + Db[i] + Dc[i];
      o.ss[i] = Sa[i] + Sb[i] + Sc[i];
      o.sd[i] = Sa[i] - Sc[i];
    }
  };

  auto emit = [&](int d, const P3& p, const P3& c, const P3& n) {
    vfloat4 o;
    #pragma unroll
    for (int i = 0; i < 4; ++i) {
      const float Gx = fmaf(2.f, c.ds[i], p.ds[i]) + n.ds[i];
      const float Gy = p.ss[i] - n.ss[i];
      const float Gz = p.sd[i] + c.sd[i] + n.sd[i];
      const int nx = (Gx != 0.f), ny = (Gy != 0.f), nz = (Gz != 0.f);
      o[i] = ((nx & ny) | (nx & nz) | (ny & nz)) ? 1.f : 0.f;
    }
    *(vfloat4*)(dst + (size_t)d * plane + offb) = o;
  };

  float4 A0, B0, C0, A1, B1, C1, A2, B2, C2;   // 3-plane raw ring
  P3 p0, p1, p2;

  // R4's schedule: 2-deep pipeline over planes d0-1 .. d0+4 (6 loads, 4 outputs)
  loadPlane(d0 - 1, A0, B0, C0);
  loadPlane(d0,     A1, B1, C1);
  loadPlane(d0 + 1, A2, B2, C2);
  partials(A0, B0, C0, p0);  loadPlane(d0 + 2, A0, B0, C0);
  partials(A1, B1, C1, p1);  loadPlane(d0 + 3, A1, B1, C1);
  partials(A2, B2, C2, p2);  loadPlane(d0 + 4, A2, B2, C2);
  emit(d0,     p0, p1, p2);
  partials(A0, B0, C0, p0);                 // plane d0+2
  emit(d0 + 1, p1, p2, p0);
  partials(A1, B1, C1, p1);                 // plane d0+3
  emit(d0 + 2, p2, p0, p1);
  partials(A2, B2, C2, p2);                 // plane d0+4
  emit(d0 + 3, p0, p1, p2);
}

__global__ __launch_bounds__(128) void sobel3d_kernel(
    const float* __restrict__ in, float* __restrict__ out) {
  const int lane = threadIdx.x;          // 0..63
  const int wg   = lane & 15;            // w-group within row (16 x float4 = row)
  const int hs   = lane >> 4;            // h-sub within wave
  const int w0   = wg * 4;
  const int h    = blockIdx.x * HT + threadIdx.y * 4 + hs;
  const int d0   = blockIdx.y * DC;
  const int b    = blockIdx.z;

  const size_t plane = (size_t)HDIM * WWID;
  const float* src = in  + (size_t)b * DDIM * plane;
  float*       dst = out + (size_t)b * DDIM * plane;
  const size_t offb = (size_t)h * WWID + w0;

  // interior blocks (62/64 of d-chunks, 30/32 of h-tiles) take the
  // guard-free path: d0-1 >= 0, d0+4 <= 255, h-1 >= 0, h+1 <= 255.
  const bool interior = (d0 > 0) & (d0 + DC < DDIM) &
                        (blockIdx.x > 0) & (blockIdx.x < gridDim.x - 1);
  if (interior) sobel_body<false>(src, dst, h, d0, offb);
  else          sobel_body<true>(src, dst, h, d0, offb);
}

extern "C" void kernel_launch(void* const* d_in, const int* in_sizes, int n_in,
                              void* d_out, int out_size, void* d_ws, size_t ws_size,
                              hipStream_t stream) {
  const float* data = (const float*)d_in[0];
  // d_in[1] = Sobel weights — fixed by the reference, folded into the kernel.
  float* out = (float*)d_out;
  dim3 grid(HDIM / HT, DDIM / DC, 4);   // (32, 64, 4) = 8192 blocks
  dim3 block(WWID, 2);                  // 128 threads = 2 waves
  sobel3d_kernel<<<grid, block, 0, stream>>>(data, out);
}

// Round 10
// 28.800 us; speedup vs baseline: 1.1185x; 1.0745x over previous
//
#include <hip/hip_runtime.h>

// Sobel3D: data [4,1,256,256,64] f32 -> out [4,1,256,256,64] f32 (0/1).
// out = 1 iff >=2 of the 3 directional Sobel gradients are nonzero.
//
// Separable decomposition (cross-correlation, SAME zero padding):
//   per (d,h) row:  S[i] = x[i-1]+2x[i]+x[i+1],  D[i] = x[i-1]-x[i+1]
//   per plane d:    ds = D(h-1)+D(h)+D(h+1), ss = S(h-1)+S(h)+S(h+1),
//                   sd = S(h-1)-S(h+1)
//   Gx = ds(d-1)+2*ds(d)+ds(d+1); Gy = ss(d-1)-ss(d+1); Gz = sd(d-1)+sd(d)+sd(d+1)
//
// R10 = exact R4 skeleton (best known: 30.3us) + XCD-aware block swizzle.
// Mechanism (T1): halo re-reads between h-neighbor and d-neighbor blocks are
// ~47% of read traffic; under default round-robin dispatch the sharers land on
// different XCDs, so re-reads are served by L3 (slow) not the 4MiB per-XCD L2.
// Swizzle gives each XCD a contiguous (batch-half x 16 h-tiles x all d) slab:
// halo sharing becomes same-XCD L2 hits.
// Invariants held from R6-R9 post-mortems: VGPR <= 64 (8 waves/SIMD), DC=4
// all-6-planes-upfront register pipeline, 8192 fine-grained blocks, plain
// stores, no LDS/barriers.

constexpr int DDIM = 256;
constexpr int HDIM = 256;
constexpr int WWID = 64;
constexpr int DC   = 4;    // output d-planes per block
constexpr int HT   = 8;    // h rows per block (2 waves)

struct P3 { float ds[4], ss[4], sd[4]; };

__device__ __forceinline__ float dpp_up1(float v) {   // lane n <- lane n-1 (16-lane row), edge->0
  return __builtin_bit_cast(float, __builtin_amdgcn_update_dpp(
      0, __builtin_bit_cast(int, v), 0x111, 0xf, 0xf, true));  // row_shr:1
}
__device__ __forceinline__ float dpp_dn1(float v) {   // lane n <- lane n+1 (16-lane row), edge->0
  return __builtin_bit_cast(float, __builtin_amdgcn_update_dpp(
      0, __builtin_bit_cast(int, v), 0x101, 0xf, 0xf, true));  // row_shl:1
}

__global__ __launch_bounds__(128) void sobel3d_kernel(
    const float* __restrict__ in, float* __restrict__ out) {
  // ---- XCD-aware swizzle (bijective: 8192 % 8 == 0) ----
  // XCD x owns swz in [x*1024, (x+1)*1024): one contiguous slab of
  // (batch b = x/2, h-tiles 16*(x&1)..16*(x&1)+15, all 64 d-chunks).
  const int bid = blockIdx.x;                    // 0..8191
  const int swz = (bid & 7) * 1024 + (bid >> 3);
  const int b   = swz >> 11;                     // /2048: batch
  const int rem = swz & 2047;
  const int hx  = rem >> 6;                      // 0..31: h-tile
  const int dx  = rem & 63;                      // 0..63: d-chunk (fastest)

  const int lane = threadIdx.x;          // 0..63
  const int wg   = lane & 15;            // w-group within row (16 x float4 = row)
  const int hs   = lane >> 4;            // h-sub within wave
  const int w0   = wg * 4;
  const int h    = hx * HT + threadIdx.y * 4 + hs;
  const int d0   = dx * DC;

  const size_t plane = (size_t)HDIM * WWID;   // 16384 floats
  const float* src = in  + (size_t)b * DDIM * plane;
  float*       dst = out + (size_t)b * DDIM * plane;

  const size_t offb = (size_t)h * WWID + w0;  // this thread's row base
  const bool va = (h > 0);                    // h-1 valid
  const bool vc = (h + 1 < HDIM);             // h+1 valid

  auto loadPlane = [&](int d, float4& ra, float4& rb, float4& rc) {
    if ((unsigned)d < (unsigned)DDIM) {
      const float* p = src + (size_t)d * plane;
      rb = *(const float4*)(p + offb);
      ra = va ? *(const float4*)(p + offb - WWID) : float4{0.f, 0.f, 0.f, 0.f};
      rc = vc ? *(const float4*)(p + offb + WWID) : float4{0.f, 0.f, 0.f, 0.f};
    } else {
      ra = rb = rc = float4{0.f, 0.f, 0.f, 0.f};
    }
  };

  // row partials S (1,2,1) and D (1,0,-1) at the 4 output w positions
  auto rowSD = [&](float4 v, float* S, float* D) {
    const float x1 = (v.x == 255.f) ? 0.f : v.x;   // reference where()
    const float x2 = (v.y == 255.f) ? 0.f : v.y;
    const float x3 = (v.z == 255.f) ? 0.f : v.z;
    const float x4 = (v.w == 255.f) ? 0.f : v.w;
    const float xm = dpp_up1(x4);   // x[w0-1] (0 at w-edge)
    const float xp = dpp_dn1(x1);   // x[w0+4] (0 at w-edge)
    const float x[6] = {xm, x1, x2, x3, x4, xp};
    #pragma unroll
    for (int i = 0; i < 4; ++i) {
      S[i] = fmaf(2.f, x[i + 1], x[i]) + x[i + 2];
      D[i] = x[i] - x[i + 2];
    }
  };

  auto partials = [&](const float4& ra, const float4& rb, const float4& rc, P3& o) {
    float Sa[4], Da[4], Sb[4], Db[4], Sc[4], Dc[4];
    rowSD(ra, Sa, Da);
    rowSD(rb, Sb, Db);
    rowSD(rc, Sc, Dc);
    #pragma unroll
    for (int i = 0; i < 4; ++i) {
      o.ds[i] = Da[i] + Db[i] + Dc[i];
      o.ss[i] = Sa[i] + Sb[i] + Sc[i];
      o.sd[i] = Sa[i] - Sc[i];
    }
  };

  auto emit = [&](int d, const P3& p, const P3& c, const P3& n) {
    float4 o;
    #pragma unroll
    for (int i = 0; i < 4; ++i) {
      const float Gx = fmaf(2.f, c.ds[i], p.ds[i]) + n.ds[i];
      const float Gy = p.ss[i] - n.ss[i];
      const float Gz = p.sd[i] + c.sd[i] + n.sd[i];
      const int cnt = (Gx != 0.f) + (Gy != 0.f) + (Gz != 0.f);
      (&o.x)[i] = (cnt >= 2) ? 1.f : 0.f;
    }
    *(float4*)(dst + (size_t)d * plane + offb) = o;
  };

  float4 A0, B0, C0, A1, B1, C1, A2, B2, C2;   // 3-plane raw ring
  P3 p0, p1, p2;

  // fully unrolled 2-deep pipeline over planes d0-1 .. d0+4 (6 loads, 4 outputs)
  loadPlane(d0 - 1, A0, B0, C0);
  loadPlane(d0,     A1, B1, C1);
  loadPlane(d0 + 1, A2, B2, C2);
  partials(A0, B0, C0, p0);  loadPlane(d0 + 2, A0, B0, C0);
  partials(A1, B1, C1, p1);  loadPlane(d0 + 3, A1, B1, C1);
  partials(A2, B2, C2, p2);  loadPlane(d0 + 4, A2, B2, C2);
  emit(d0,     p0, p1, p2);
  partials(A0, B0, C0, p0);                 // plane d0+2
  emit(d0 + 1, p1, p2, p0);
  partials(A1, B1, C1, p1);                 // plane d0+3
  emit(d0 + 2, p2, p0, p1);
  partials(A2, B2, C2, p2);                 // plane d0+4
  emit(d0 + 3, p0, p1, p2);
}

extern "C" void kernel_launch(void* const* d_in, const int* in_sizes, int n_in,
                              void* d_out, int out_size, void* d_ws, size_t ws_size,
                              hipStream_t stream) {
  const float* data = (const float*)d_in[0];
  // d_in[1] = Sobel weights — fixed by the reference, folded into the kernel.
  float* out = (float*)d_out;
  dim3 grid(8192);                       // 1D; swizzle decoded in-kernel
  dim3 block(WWID, 2);                   // 128 threads = 2 waves
  sobel3d_kernel<<<grid, block, 0, stream>>>(data, out);
}